// Round 2
// baseline (716.302 us; speedup 1.0000x reference)
//
#include <hip/hip_runtime.h>
#include <hip/hip_bf16.h>

// SparseNoisyMoE: B=8192, IN=512, OUT=720, E=16, K=2, MOE_TEMP=1.0 (eval mode)
// R2: (a) gate rewrite -> 256 rows/block, LDS histograms, ~512 global atomics
//     (vs 32K in R1 -- suspected ~100us of the 156us non-moe gap);
//     (b) expert GEMM in bf16 MFMA (16x16x32), 64x64 tile, BK=64.
//     fp32 fallback kept if ws_size too small for bf16 staging buffers.

#define BATCH 8192
#define IND   512
#define OUTD  720
#define NEXP  16

typedef __attribute__((ext_vector_type(8))) short short8;
typedef __attribute__((ext_vector_type(4))) float floatx4;

__device__ __forceinline__ unsigned short f2bf(float f) {
    union { float f; unsigned u; } v; v.f = f;
    unsigned r = v.u + 0x7FFFu + ((v.u >> 16) & 1u);   // RNE
    return (unsigned short)(r >> 16);
}

// ---------------- gating: 256 rows per block, 32 blocks ----------------
__global__ __launch_bounds__(256) void gate_kernel2(
    const float* __restrict__ x, const float* __restrict__ Wg,
    const float* __restrict__ bg,
    int* __restrict__ counts, float* __restrict__ Psum, float* __restrict__ Dsum,
    float* __restrict__ gates, unsigned short* __restrict__ lists)
{
    __shared__ float sg[256][17];
    __shared__ float Ploc[16], Dloc[16];
    __shared__ int   cnt_loc[16], base_loc[16], off_loc[16];
    int tid = threadIdx.x;
    if (tid < 16) { Ploc[tid] = 0.f; Dloc[tid] = 0.f; cnt_loc[tid] = 0; off_loc[tid] = 0; }
    __syncthreads();

    int rbase = blockIdx.x * 256;
    int rsub  = tid >> 4;
    int e     = tid & 15;

    // phase 1: gate matrix. thread (rsub,e) covers rows rbase + c*16 + rsub.
    for (int c = 0; c < 16; ++c) {
        int r = c * 16 + rsub;
        const float4* x4 = (const float4*)(x + (size_t)(rbase + r) * IND);
        float acc = bg[e];
        #pragma unroll 8
        for (int i4 = 0; i4 < IND / 4; ++i4) {
            float4 xv = x4[i4];
            int ib = i4 * 4;
            acc += xv.x * Wg[(ib + 0) * NEXP + e];
            acc += xv.y * Wg[(ib + 1) * NEXP + e];
            acc += xv.z * Wg[(ib + 2) * NEXP + e];
            acc += xv.w * Wg[(ib + 3) * NEXP + e];
        }
        sg[r][e] = acc;    // MOE_TEMP == 1.0
    }
    __syncthreads();

    // phase 2: one thread per row
    int row = rbase + tid;
    float v0 = -1e30f, v1 = -1e30f; int i0 = 0, i1 = 0;
    float g[16];
    #pragma unroll
    for (int ee = 0; ee < 16; ++ee) {
        float v = sg[tid][ee]; g[ee] = v;
        if (v > v0)      { v1 = v0; i1 = i0; v0 = v; i0 = ee; }
        else if (v > v1) { v1 = v;  i1 = ee; }
    }
    float e1   = expf(v1 - v0);
    float inv2 = 1.f / (1.f + e1);
    gates[row * 2 + 0] = inv2;
    gates[row * 2 + 1] = e1 * inv2;

    float s = 0.f, pr[16];
    #pragma unroll
    for (int ee = 0; ee < 16; ++ee) { pr[ee] = expf(g[ee] - v0); s += pr[ee]; }
    float invs = 1.f / s;
    #pragma unroll
    for (int ee = 0; ee < 16; ++ee) atomicAdd(&Ploc[ee], pr[ee] * invs);
    atomicAdd(&Dloc[i0], 1.f);
    atomicAdd(&cnt_loc[i0], 1);
    atomicAdd(&cnt_loc[i1], 1);
    __syncthreads();

    if (tid < 16) {
        base_loc[tid] = atomicAdd(&counts[tid], cnt_loc[tid]);
        atomicAdd(&Psum[tid], Ploc[tid]);
        atomicAdd(&Dsum[tid], Dloc[tid]);
    }
    __syncthreads();

    int p0 = base_loc[i0] + atomicAdd(&off_loc[i0], 1);
    lists[i0 * BATCH + p0] = (unsigned short)(row << 1);
    int p1 = base_loc[i1] + atomicAdd(&off_loc[i1], 1);
    lists[i1 * BATCH + p1] = (unsigned short)((row << 1) | 1);
}

// ---------------- conversions ----------------
__global__ __launch_bounds__(256) void convert_x_kernel(
    const float* __restrict__ x, unsigned short* __restrict__ xb)
{
    int i = blockIdx.x * 256 + threadIdx.x;           // one float4 each
    const float4* x4 = (const float4*)x;
    float4 v = x4[i];
    ushort4 o;
    o.x = f2bf(v.x); o.y = f2bf(v.y); o.z = f2bf(v.z); o.w = f2bf(v.w);
    ((ushort4*)xb)[i] = o;
}

// We[e][k][o] fp32 -> Wt[e][o][k] bf16 (32x32 tiles)
__global__ __launch_bounds__(256) void transpose_We_kernel(
    const float* __restrict__ We, unsigned short* __restrict__ Wt)
{
    __shared__ float tile[32][33];
    int e  = blockIdx.z;
    int ob = blockIdx.x * 32;
    int kb = blockIdx.y * 32;
    int tx = threadIdx.x & 31, ty = threadIdx.x >> 5;   // ty 0..7
    const float* src = We + (size_t)e * (IND * OUTD);
    #pragma unroll
    for (int j = 0; j < 4; ++j) {
        int kk = ty * 4 + j;
        int o  = ob + tx;
        tile[kk][tx] = (o < OUTD) ? src[(size_t)(kb + kk) * OUTD + o] : 0.f;
    }
    __syncthreads();
    unsigned short* dst = Wt + (size_t)e * (OUTD * IND);
    #pragma unroll
    for (int j = 0; j < 4; ++j) {
        int o = ob + ty * 4 + j;
        if (o < OUTD) dst[(size_t)o * IND + kb + tx] = f2bf(tile[tx][ty * 4 + j]);
    }
}

// ---------------- bf16 MFMA expert gather-GEMM ----------------
// 64 rows x 64 cols per block, BK=64, 4 waves each own a 32x32 quadrant.
__global__ __launch_bounds__(256) void moe_mfma_kernel(
    const unsigned short* __restrict__ xb, const unsigned short* __restrict__ Wt,
    const float* __restrict__ be,
    const int* __restrict__ counts, const float* __restrict__ gates,
    const unsigned short* __restrict__ lists, float* __restrict__ out)
{
    int e = blockIdx.z;
    int n = counts[e];
    int r0 = blockIdx.y * 64;
    if (r0 >= n) return;
    int n0 = blockIdx.x * 64;

    __shared__ unsigned short sA[64][72];   // [row][k], stride 144B: 16B-aligned, 2-way bank alias (free)
    __shared__ unsigned short sB[64][72];   // [col][k]
    __shared__ int   srow[64];
    __shared__ float sgw[64];

    int tid = threadIdx.x;
    if (tid < 64) {
        int idx = r0 + tid;
        if (idx < n) {
            int ent = lists[e * BATCH + idx];
            srow[tid] = ent >> 1;
            sgw[tid]  = gates[(ent >> 1) * 2 + (ent & 1)];
        } else { srow[tid] = 0; sgw[tid] = 0.f; }
    }
    __syncthreads();

    int lane = tid & 63, wave = tid >> 6;
    int mbase = (wave & 1) * 32, nbase = (wave >> 1) * 32;
    int l15 = lane & 15, quad = lane >> 4;

    floatx4 acc00 = {0.f,0.f,0.f,0.f}, acc01 = {0.f,0.f,0.f,0.f};
    floatx4 acc10 = {0.f,0.f,0.f,0.f}, acc11 = {0.f,0.f,0.f,0.f};

    // staging: thread t -> row/col t>>2, 16B chunk (t&3)*8, twice (k and k+32)
    int arow = tid >> 2, aq = tid & 3;
    const unsigned short* aptr = xb + (size_t)srow[arow] * IND + aq * 8;
    int gcol = n0 + arow;
    const unsigned short* bptr = Wt + ((size_t)e * OUTD + (gcol < OUTD ? gcol : 0)) * IND + aq * 8;
    bool bok = gcol < OUTD;
    short8 zz = {0,0,0,0,0,0,0,0};

    for (int kt = 0; kt < IND / 64; ++kt) {
        short8 av0 = *(const short8*)(aptr + kt * 64);
        short8 av1 = *(const short8*)(aptr + kt * 64 + 32);
        short8 bv0 = bok ? *(const short8*)(bptr + kt * 64)      : zz;
        short8 bv1 = bok ? *(const short8*)(bptr + kt * 64 + 32) : zz;
        __syncthreads();
        *(short8*)&sA[arow][aq * 8]      = av0;
        *(short8*)&sA[arow][aq * 8 + 32] = av1;
        *(short8*)&sB[arow][aq * 8]      = bv0;
        *(short8*)&sB[arow][aq * 8 + 32] = bv1;
        __syncthreads();
        #pragma unroll
        for (int ks = 0; ks < 2; ++ks) {
            int ko = ks * 32 + quad * 8;
            short8 a0 = *(const short8*)&sA[mbase + l15][ko];
            short8 a1 = *(const short8*)&sA[mbase + 16 + l15][ko];
            short8 b0 = *(const short8*)&sB[nbase + l15][ko];
            short8 b1 = *(const short8*)&sB[nbase + 16 + l15][ko];
            acc00 = __builtin_amdgcn_mfma_f32_16x16x32_bf16(a0, b0, acc00, 0, 0, 0);
            acc01 = __builtin_amdgcn_mfma_f32_16x16x32_bf16(a0, b1, acc01, 0, 0, 0);
            acc10 = __builtin_amdgcn_mfma_f32_16x16x32_bf16(a1, b0, acc10, 0, 0, 0);
            acc11 = __builtin_amdgcn_mfma_f32_16x16x32_bf16(a1, b1, acc11, 0, 0, 0);
        }
    }

    // epilogue: C/D layout col=lane&15, row=quad*4+i  [m89]
    #pragma unroll
    for (int nsub = 0; nsub < 2; ++nsub) {
        int col = n0 + nbase + nsub * 16 + l15;
        if (col < OUTD) {
            float bev = be[e * OUTD + col];
            #pragma unroll
            for (int msub = 0; msub < 2; ++msub) {
                const floatx4& a = msub ? (nsub ? acc11 : acc10) : (nsub ? acc01 : acc00);
                #pragma unroll
                for (int i = 0; i < 4; ++i) {
                    int lm = mbase + msub * 16 + quad * 4 + i;
                    if (r0 + lm < n) {
                        atomicAdd(&out[(size_t)srow[lm] * OUTD + col],
                                  sgw[lm] * (a[i] + bev));
                    }
                }
            }
        }
    }
}

// ---------------- fp32 fallback gather-GEMM (R1 kernel) ----------------
__global__ __launch_bounds__(256) void moe_kernel(
    const float* __restrict__ x, const float* __restrict__ We,
    const float* __restrict__ be,
    const int* __restrict__ counts, const float* __restrict__ gates,
    const unsigned short* __restrict__ lists, float* __restrict__ out)
{
    int e = blockIdx.z;
    int n = counts[e];
    int r0 = blockIdx.y * 64;
    if (r0 >= n) return;
    int n0 = blockIdx.x * 64;

    __shared__ float sA[16][64];
    __shared__ float sB[16][64];
    __shared__ int   srow[64];
    __shared__ float sgw[64];

    int tid = threadIdx.x;
    if (tid < 64) {
        int idx = r0 + tid;
        if (idx < n) {
            int ent = lists[e * BATCH + idx];
            srow[tid] = ent >> 1;
            sgw[tid]  = gates[(ent >> 1) * 2 + (ent & 1)];
        } else { srow[tid] = 0; sgw[tid] = 0.f; }
    }
    __syncthreads();

    int tm = tid >> 4, tn = tid & 15;
    float acc[4][4] = {};
    const float* Be = We + (size_t)e * (IND * OUTD);
    int ar = tid >> 2, ac4 = tid & 3;
    int bk = tid >> 4, bc4 = tid & 15;
    const float* aptr = x + (size_t)srow[ar] * IND + ac4 * 4;
    int gcol = n0 + bc4 * 4;
    bool bok = (gcol < OUTD);

    for (int kt = 0; kt < IND / 16; ++kt) {
        float4 av = *(const float4*)(aptr + kt * 16);
        float4 bv = make_float4(0.f, 0.f, 0.f, 0.f);
        if (bok) bv = *(const float4*)(Be + (size_t)(kt * 16 + bk) * OUTD + gcol);
        __syncthreads();
        sA[ac4 * 4 + 0][ar] = av.x;
        sA[ac4 * 4 + 1][ar] = av.y;
        sA[ac4 * 4 + 2][ar] = av.z;
        sA[ac4 * 4 + 3][ar] = av.w;
        *(float4*)&sB[bk][bc4 * 4] = bv;
        __syncthreads();
        #pragma unroll
        for (int kk = 0; kk < 16; ++kk) {
            float4 a = *(const float4*)&sA[kk][tm * 4];
            float4 b = *(const float4*)&sB[kk][tn * 4];
            acc[0][0] += a.x * b.x; acc[0][1] += a.x * b.y; acc[0][2] += a.x * b.z; acc[0][3] += a.x * b.w;
            acc[1][0] += a.y * b.x; acc[1][1] += a.y * b.y; acc[1][2] += a.y * b.z; acc[1][3] += a.y * b.w;
            acc[2][0] += a.z * b.x; acc[2][1] += a.z * b.y; acc[2][2] += a.z * b.z; acc[2][3] += a.z * b.w;
            acc[3][0] += a.w * b.x; acc[3][1] += a.w * b.y; acc[3][2] += a.w * b.z; acc[3][3] += a.w * b.w;
        }
    }
    #pragma unroll
    for (int i = 0; i < 4; ++i) {
        int lr = tm * 4 + i;
        if (r0 + lr < n) {
            int   row = srow[lr];
            float gw  = sgw[lr];
            #pragma unroll
            for (int j = 0; j < 4; ++j) {
                int col = n0 + tn * 4 + j;
                if (col < OUTD)
                    atomicAdd(&out[(size_t)row * OUTD + col],
                              gw * (acc[i][j] + be[e * OUTD + col]));
            }
        }
    }
}

// ---------------- load-balance loss ----------------
__global__ void loss_kernel(const float* __restrict__ Psum,
                            const float* __restrict__ Dsum,
                            float* __restrict__ out)
{
    if (threadIdx.x == 0) {
        float s = 0.f;
        #pragma unroll
        for (int e = 0; e < NEXP; ++e)
            s += (Dsum[e] / (float)BATCH) * (Psum[e] / (float)BATCH);
        out[(size_t)BATCH * OUTD] = s * (float)NEXP;
    }
}

extern "C" void kernel_launch(void* const* d_in, const int* in_sizes, int n_in,
                              void* d_out, int out_size, void* d_ws, size_t ws_size,
                              hipStream_t stream)
{
    const float* x  = (const float*)d_in[0];
    const float* Wg = (const float*)d_in[1];
    const float* bg = (const float*)d_in[2];
    const float* We = (const float*)d_in[3];
    const float* be = (const float*)d_in[4];
    float* out = (float*)d_out;

    char* ws = (char*)d_ws;
    int*   counts = (int*)ws;                         // 16 ints
    float* Psum   = (float*)(ws + 64);                // 16 floats
    float* Dsum   = (float*)(ws + 128);               // 16 floats
    float* gates  = (float*)(ws + 256);               // B*2 floats = 64 KB
    unsigned short* lists = (unsigned short*)(ws + 256 + BATCH * 2 * sizeof(float)); // 256 KB
    size_t off_xb = 256 + (size_t)BATCH * 2 * 4 + (size_t)NEXP * BATCH * 2;
    off_xb = (off_xb + 255) & ~(size_t)255;
    unsigned short* xb = (unsigned short*)(ws + off_xb);                    // 8.39 MB
    size_t off_wt = off_xb + (size_t)BATCH * IND * 2;
    unsigned short* Wt = (unsigned short*)(ws + off_wt);                    // 11.80 MB
    size_t req = off_wt + (size_t)NEXP * OUTD * IND * 2;

    hipMemsetAsync(ws, 0, 256, stream);
    hipMemsetAsync(d_out, 0, (size_t)out_size * sizeof(float), stream);

    gate_kernel2<<<BATCH / 256, 256, 0, stream>>>(x, Wg, bg, counts, Psum, Dsum, gates, lists);

    if (ws_size >= req) {
        convert_x_kernel<<<(BATCH * IND / 4) / 256, 256, 0, stream>>>(x, xb);
        dim3 tgrid((OUTD + 31) / 32, IND / 32, NEXP);
        transpose_We_kernel<<<tgrid, 256, 0, stream>>>(We, Wt);
        dim3 grid((OUTD + 63) / 64, BATCH / 64, NEXP);
        moe_mfma_kernel<<<grid, 256, 0, stream>>>(xb, Wt, be, counts, gates, lists, out);
    } else {
        dim3 grid((OUTD + 63) / 64, BATCH / 64, NEXP);
        moe_kernel<<<grid, 256, 0, stream>>>(x, We, be, counts, gates, lists, out);
    }

    loss_kernel<<<1, 64, 0, stream>>>(Psum, Dsum, out);
}

// Round 3
// 188.014 us; speedup vs baseline: 3.8098x; 3.8098x over previous
//
#include <hip/hip_runtime.h>
#include <hip/hip_bf16.h>

// SparseNoisyMoE: B=8192, IN=512, OUT=720, E=16, K=2, MOE_TEMP=1.0 (eval mode)
// R3: gate rewrite -> 512 blocks (16 rows each, restores occupancy; R2's 32-block
// version was 1.4% occupancy / 585us), x+Wg staged in LDS, and all small global
// accumulators padded to one-per-64B-line to kill same-line atomic serialization.
// moe path unchanged from R2 (bf16 MFMA 64x64 tile) -- profiled next round.

#define BATCH 8192
#define IND   512
#define OUTD  720
#define NEXP  16
#define CPAD  16   // pad small counters to 16 elements (64 B) per expert

typedef __attribute__((ext_vector_type(8))) short short8;
typedef __attribute__((ext_vector_type(4))) float floatx4;

__device__ __forceinline__ unsigned short f2bf(float f) {
    union { float f; unsigned u; } v; v.f = f;
    unsigned r = v.u + 0x7FFFu + ((v.u >> 16) & 1u);   // RNE
    return (unsigned short)(r >> 16);
}

// ---------------- gating: 16 rows/block, 512 blocks ----------------
__global__ __launch_bounds__(256) void gate_kernel3(
    const float* __restrict__ x, const float* __restrict__ Wg,
    const float* __restrict__ bg,
    int* __restrict__ counts, float* __restrict__ Psum, float* __restrict__ Dsum,
    float* __restrict__ gates, unsigned short* __restrict__ lists)
{
    __shared__ float sx[16][512];     // 32 KB: 16 rows of x
    __shared__ float sWg[16][516];    // 33 KB: Wg transposed, +4 pad -> 2-way banks
    __shared__ float sg[16][17];
    __shared__ float Ploc[16], Dloc[16];
    __shared__ int   cnt_loc[16], base_loc[16], off_loc[16];

    int tid = threadIdx.x;
    if (tid < 16) { Ploc[tid] = 0.f; Dloc[tid] = 0.f; cnt_loc[tid] = 0; off_loc[tid] = 0; }

    int rbase = blockIdx.x * 16;

    // stage x rows: 2048 float4, coalesced, 8 per thread
    const float4* gx4 = (const float4*)(x + (size_t)rbase * IND);
    #pragma unroll
    for (int j = 0; j < 8; ++j) {
        int f = tid + j * 256;        // 0..2047
        int r = f >> 7;               // /128
        int c = f & 127;
        *(float4*)&sx[r][c * 4] = gx4[f];
    }
    // stage Wg transposed: Wg[i][e] -> sWg[e][i]; 2048 float4 coalesced reads
    const float4* gw4 = (const float4*)Wg;
    #pragma unroll
    for (int j = 0; j < 8; ++j) {
        int f = tid + j * 256;
        float4 v = gw4[f];
        int i  = f >> 2;
        int e0 = (f & 3) * 4;
        sWg[e0 + 0][i] = v.x;
        sWg[e0 + 1][i] = v.y;
        sWg[e0 + 2][i] = v.z;
        sWg[e0 + 3][i] = v.w;
    }
    __syncthreads();

    // phase 1: thread (r,e) dot
    int r = tid >> 4, e = tid & 15;
    const float4* xr = (const float4*)&sx[r][0];
    const float4* wr = (const float4*)&sWg[e][0];
    float acc = bg[e];
    #pragma unroll 8
    for (int i4 = 0; i4 < 128; ++i4) {
        float4 a = xr[i4], w = wr[i4];
        acc += a.x * w.x + a.y * w.y + a.z * w.z + a.w * w.w;
    }
    sg[r][e] = acc;    // MOE_TEMP == 1.0
    __syncthreads();

    // phase 2: one thread per row (tid < 16)
    int i0 = 0, i1 = 0;
    if (tid < 16) {
        int row = rbase + tid;
        float v0 = -1e30f, v1 = -1e30f;
        float g[16];
        #pragma unroll
        for (int ee = 0; ee < 16; ++ee) {
            float v = sg[tid][ee]; g[ee] = v;
            if (v > v0)      { v1 = v0; i1 = i0; v0 = v; i0 = ee; }
            else if (v > v1) { v1 = v;  i1 = ee; }
        }
        float e1   = expf(v1 - v0);
        float inv2 = 1.f / (1.f + e1);
        gates[row * 2 + 0] = inv2;
        gates[row * 2 + 1] = e1 * inv2;

        float s = 0.f, pr[16];
        #pragma unroll
        for (int ee = 0; ee < 16; ++ee) { pr[ee] = expf(g[ee] - v0); s += pr[ee]; }
        float invs = 1.f / s;
        #pragma unroll
        for (int ee = 0; ee < 16; ++ee) atomicAdd(&Ploc[ee], pr[ee] * invs);
        atomicAdd(&Dloc[i0], 1.f);
        atomicAdd(&cnt_loc[i0], 1);
        atomicAdd(&cnt_loc[i1], 1);
    }
    __syncthreads();

    if (tid < 16) {
        // padded global accumulators: one per 64B line
        if (cnt_loc[tid] > 0) base_loc[tid] = atomicAdd(&counts[tid * CPAD], cnt_loc[tid]);
        atomicAdd(&Psum[tid * CPAD], Ploc[tid]);
        atomicAdd(&Dsum[tid * CPAD], Dloc[tid]);
    }
    __syncthreads();

    if (tid < 16) {
        int row = rbase + tid;
        int p0 = base_loc[i0] + atomicAdd(&off_loc[i0], 1);
        lists[i0 * BATCH + p0] = (unsigned short)(row << 1);
        int p1 = base_loc[i1] + atomicAdd(&off_loc[i1], 1);
        lists[i1 * BATCH + p1] = (unsigned short)((row << 1) | 1);
    }
}

// ---------------- conversions ----------------
__global__ __launch_bounds__(256) void convert_x_kernel(
    const float* __restrict__ x, unsigned short* __restrict__ xb)
{
    int i = blockIdx.x * 256 + threadIdx.x;           // one float4 each
    const float4* x4 = (const float4*)x;
    float4 v = x4[i];
    ushort4 o;
    o.x = f2bf(v.x); o.y = f2bf(v.y); o.z = f2bf(v.z); o.w = f2bf(v.w);
    ((ushort4*)xb)[i] = o;
}

// We[e][k][o] fp32 -> Wt[e][o][k] bf16 (32x32 tiles)
__global__ __launch_bounds__(256) void transpose_We_kernel(
    const float* __restrict__ We, unsigned short* __restrict__ Wt)
{
    __shared__ float tile[32][33];
    int e  = blockIdx.z;
    int ob = blockIdx.x * 32;
    int kb = blockIdx.y * 32;
    int tx = threadIdx.x & 31, ty = threadIdx.x >> 5;   // ty 0..7
    const float* src = We + (size_t)e * (IND * OUTD);
    #pragma unroll
    for (int j = 0; j < 4; ++j) {
        int kk = ty * 4 + j;
        int o  = ob + tx;
        tile[kk][tx] = (o < OUTD) ? src[(size_t)(kb + kk) * OUTD + o] : 0.f;
    }
    __syncthreads();
    unsigned short* dst = Wt + (size_t)e * (OUTD * IND);
    #pragma unroll
    for (int j = 0; j < 4; ++j) {
        int o = ob + ty * 4 + j;
        if (o < OUTD) dst[(size_t)o * IND + kb + tx] = f2bf(tile[tx][ty * 4 + j]);
    }
}

// ---------------- bf16 MFMA expert gather-GEMM ----------------
// 64 rows x 64 cols per block, BK=64, 4 waves each own a 32x32 quadrant.
__global__ __launch_bounds__(256) void moe_mfma_kernel(
    const unsigned short* __restrict__ xb, const unsigned short* __restrict__ Wt,
    const float* __restrict__ be,
    const int* __restrict__ counts, const float* __restrict__ gates,
    const unsigned short* __restrict__ lists, float* __restrict__ out)
{
    int e = blockIdx.z;
    int n = counts[e * CPAD];
    int r0 = blockIdx.y * 64;
    if (r0 >= n) return;
    int n0 = blockIdx.x * 64;

    __shared__ unsigned short sA[64][72];   // [row][k], stride 144B
    __shared__ unsigned short sB[64][72];   // [col][k]
    __shared__ int   srow[64];
    __shared__ float sgw[64];

    int tid = threadIdx.x;
    if (tid < 64) {
        int idx = r0 + tid;
        if (idx < n) {
            int ent = lists[e * BATCH + idx];
            srow[tid] = ent >> 1;
            sgw[tid]  = gates[(ent >> 1) * 2 + (ent & 1)];
        } else { srow[tid] = 0; sgw[tid] = 0.f; }
    }
    __syncthreads();

    int lane = tid & 63, wave = tid >> 6;
    int mbase = (wave & 1) * 32, nbase = (wave >> 1) * 32;
    int l15 = lane & 15, quad = lane >> 4;

    floatx4 acc00 = {0.f,0.f,0.f,0.f}, acc01 = {0.f,0.f,0.f,0.f};
    floatx4 acc10 = {0.f,0.f,0.f,0.f}, acc11 = {0.f,0.f,0.f,0.f};

    int arow = tid >> 2, aq = tid & 3;
    const unsigned short* aptr = xb + (size_t)srow[arow] * IND + aq * 8;
    int gcol = n0 + arow;
    const unsigned short* bptr = Wt + ((size_t)e * OUTD + (gcol < OUTD ? gcol : 0)) * IND + aq * 8;
    bool bok = gcol < OUTD;
    short8 zz = {0,0,0,0,0,0,0,0};

    for (int kt = 0; kt < IND / 64; ++kt) {
        short8 av0 = *(const short8*)(aptr + kt * 64);
        short8 av1 = *(const short8*)(aptr + kt * 64 + 32);
        short8 bv0 = bok ? *(const short8*)(bptr + kt * 64)      : zz;
        short8 bv1 = bok ? *(const short8*)(bptr + kt * 64 + 32) : zz;
        __syncthreads();
        *(short8*)&sA[arow][aq * 8]      = av0;
        *(short8*)&sA[arow][aq * 8 + 32] = av1;
        *(short8*)&sB[arow][aq * 8]      = bv0;
        *(short8*)&sB[arow][aq * 8 + 32] = bv1;
        __syncthreads();
        #pragma unroll
        for (int ks = 0; ks < 2; ++ks) {
            int ko = ks * 32 + quad * 8;
            short8 a0 = *(const short8*)&sA[mbase + l15][ko];
            short8 a1 = *(const short8*)&sA[mbase + 16 + l15][ko];
            short8 b0 = *(const short8*)&sB[nbase + l15][ko];
            short8 b1 = *(const short8*)&sB[nbase + 16 + l15][ko];
            acc00 = __builtin_amdgcn_mfma_f32_16x16x32_bf16(a0, b0, acc00, 0, 0, 0);
            acc01 = __builtin_amdgcn_mfma_f32_16x16x32_bf16(a0, b1, acc01, 0, 0, 0);
            acc10 = __builtin_amdgcn_mfma_f32_16x16x32_bf16(a1, b0, acc10, 0, 0, 0);
            acc11 = __builtin_amdgcn_mfma_f32_16x16x32_bf16(a1, b1, acc11, 0, 0, 0);
        }
    }

    // epilogue: C/D layout col=lane&15, row=quad*4+i  [m89]
    #pragma unroll
    for (int nsub = 0; nsub < 2; ++nsub) {
        int col = n0 + nbase + nsub * 16 + l15;
        if (col < OUTD) {
            float bev = be[e * OUTD + col];
            #pragma unroll
            for (int msub = 0; msub < 2; ++msub) {
                const floatx4& a = msub ? (nsub ? acc11 : acc10) : (nsub ? acc01 : acc00);
                #pragma unroll
                for (int i = 0; i < 4; ++i) {
                    int lm = mbase + msub * 16 + quad * 4 + i;
                    if (r0 + lm < n) {
                        atomicAdd(&out[(size_t)srow[lm] * OUTD + col],
                                  sgw[lm] * (a[i] + bev));
                    }
                }
            }
        }
    }
}

// ---------------- load-balance loss ----------------
__global__ void loss_kernel(const float* __restrict__ Psum,
                            const float* __restrict__ Dsum,
                            float* __restrict__ out)
{
    if (threadIdx.x == 0) {
        float s = 0.f;
        #pragma unroll
        for (int e = 0; e < NEXP; ++e)
            s += (Dsum[e * CPAD] / (float)BATCH) * (Psum[e * CPAD] / (float)BATCH);
        out[(size_t)BATCH * OUTD] = s * (float)NEXP;
    }
}

extern "C" void kernel_launch(void* const* d_in, const int* in_sizes, int n_in,
                              void* d_out, int out_size, void* d_ws, size_t ws_size,
                              hipStream_t stream)
{
    const float* x  = (const float*)d_in[0];
    const float* Wg = (const float*)d_in[1];
    const float* bg = (const float*)d_in[2];
    const float* We = (const float*)d_in[3];
    const float* be = (const float*)d_in[4];
    float* out = (float*)d_out;

    char* ws = (char*)d_ws;
    int*   counts = (int*)ws;                         // 16 padded ints  (1 KB)
    float* Psum   = (float*)(ws + 1024);              // 16 padded floats
    float* Dsum   = (float*)(ws + 2048);              // 16 padded floats
    float* gates  = (float*)(ws + 4096);              // B*2 floats = 64 KB
    unsigned short* lists = (unsigned short*)(ws + 4096 + BATCH * 2 * sizeof(float)); // 256 KB
    size_t off_xb = 4096 + (size_t)BATCH * 2 * 4 + (size_t)NEXP * BATCH * 2;
    off_xb = (off_xb + 255) & ~(size_t)255;
    unsigned short* xb = (unsigned short*)(ws + off_xb);                    // 8.39 MB
    size_t off_wt = off_xb + (size_t)BATCH * IND * 2;
    unsigned short* Wt = (unsigned short*)(ws + off_wt);                    // 11.80 MB
    size_t req = off_wt + (size_t)NEXP * OUTD * IND * 2;

    hipMemsetAsync(ws, 0, 4096, stream);
    hipMemsetAsync(d_out, 0, (size_t)out_size * sizeof(float), stream);

    gate_kernel3<<<BATCH / 16, 256, 0, stream>>>(x, Wg, bg, counts, Psum, Dsum, gates, lists);

    dim3 grid((OUTD + 63) / 64, BATCH / 64, NEXP);
    if (ws_size >= req) {
        convert_x_kernel<<<(BATCH * IND / 4) / 256, 256, 0, stream>>>(x, xb);
        dim3 tgrid((OUTD + 31) / 32, IND / 32, NEXP);
        transpose_We_kernel<<<tgrid, 256, 0, stream>>>(We, Wt);
        moe_mfma_kernel<<<grid, 256, 0, stream>>>(xb, Wt, be, counts, gates, lists, out);
    }

    loss_kernel<<<1, 64, 0, stream>>>(Psum, Dsum, out);
}